// Round 2
// baseline (969.240 us; speedup 1.0000x reference)
//
#include <hip/hip_runtime.h>
#include <stdint.h>

#define NN 2048
#define FF 64
#define NB 32

typedef __attribute__((ext_vector_type(8))) short bf16x8;
typedef __attribute__((ext_vector_type(4))) float f32x4;

__device__ __forceinline__ uint16_t f2bf(float f) {
  uint32_t u = __builtin_bit_cast(uint32_t, f);
  return (uint16_t)((u + 0x7FFFu + ((u >> 16) & 1u)) >> 16);  // RNE
}
__device__ __forceinline__ float bf2f(uint16_t h) {
  uint32_t u = ((uint32_t)h) << 16;
  return __builtin_bit_cast(float, u);
}

// ---------------- W [64(k)][64(f)] fp32 -> Wt [64(f)][64(k)] bf16 ----------------
__global__ void k_prep(const float* __restrict__ W, uint16_t* __restrict__ Wt) {
  int t = threadIdx.x;  // 256
  for (int i = 0; i < 16; ++i) {
    int idx = t * 16 + i;  // = k*64 + f
    int k = idx >> 6, f = idx & 63;
    Wt[f * 64 + k] = f2bf(W[idx]);
  }
}

// ---------------- xw = x @ W ; writes xw_n [b][n][f] AND xwT [b][f][n] -----------
// 16-row tile. wave w handles f-chunk w*16..w*16+15.
__global__ __launch_bounds__(256, 4) void k_xw(const float* __restrict__ x,
                                               const uint16_t* __restrict__ Wt,
                                               uint16_t* __restrict__ xw_n,
                                               uint16_t* __restrict__ xwT) {
  __shared__ short Xs[16 * 72];  // stride 72 shorts; frag-read bank groups (l16+q)%8 uniform
  __shared__ short T[64 * 20];   // transpose buffer [f][n_local], stride 20
  int bid = blockIdx.x;
  int b = bid & 31;              // batch-minor: batch pinned to XCD b%8
  int row0 = (bid >> 5) * 16;    // 128 row-blocks
  int t = threadIdx.x;
  int lane = t & 63, wv = t >> 6, l16 = lane & 15, quad = lane >> 4;

  int sr = t >> 4, sc = (t & 15) * 4;
  float4 v = *(const float4*)(x + ((size_t)b * NN + row0 + sr) * FF + sc);
  uint32_t p0 = f2bf(v.x) | ((uint32_t)f2bf(v.y) << 16);
  uint32_t p1 = f2bf(v.z) | ((uint32_t)f2bf(v.w) << 16);
  uint2 pv = {p0, p1};
  *(uint2*)&Xs[sr * 72 + sc] = pv;
  __syncthreads();

  f32x4 acc = {};
#pragma unroll
  for (int s = 0; s < 2; ++s) {
    bf16x8 a = *(const bf16x8*)&Xs[l16 * 72 + s * 32 + quad * 8];
    bf16x8 bq = *(const bf16x8*)(Wt + (size_t)(wv * 16 + l16) * 64 + s * 32 + quad * 8);
    acc = __builtin_amdgcn_mfma_f32_16x16x32_bf16(a, bq, acc, 0, 0, 0);
  }
  int f = wv * 16 + l16;
#pragma unroll
  for (int r = 0; r < 4; ++r)
    xw_n[((size_t)b * NN + row0 + quad * 4 + r) * FF + f] = f2bf(acc[r]);
  uint32_t q0 = f2bf(acc[0]) | ((uint32_t)f2bf(acc[1]) << 16);
  uint32_t q1 = f2bf(acc[2]) | ((uint32_t)f2bf(acc[3]) << 16);
  uint2 qv = {q0, q1};
  *(uint2*)&T[f * 20 + quad * 4] = qv;
  __syncthreads();
  int f2 = t >> 2, nc = (t & 3) * 4;
  uint2 w2 = *(const uint2*)&T[f2 * 20 + nc];
  *(uint2*)(xwT + ((size_t)b * FF + f2) * NN + row0 + nc) = w2;
}

// ---------------- Y = A @ X ; A fp32 [2048][2048], Bt bf16 [64][2048] ------------
// 16-row tile, K-chunk 256 staged in LDS (A only); B frags read direct from L2.
// EPI=0: write Yn [b][n][f] bf16 + Yt [b][f][n] bf16.
// EPI=1: out = ka*xw + kb*y1 + kc*Y + bias (fp32).
template <int EPI>
__global__ __launch_bounds__(256, 4) void k_gemm(const float* __restrict__ adj,
                                                 const uint16_t* __restrict__ Bt,
                                                 uint16_t* __restrict__ Yn,
                                                 uint16_t* __restrict__ Yt,
                                                 const uint16_t* __restrict__ xw,
                                                 const uint16_t* __restrict__ y1,
                                                 const float* __restrict__ Kc,
                                                 const float* __restrict__ bias,
                                                 float* __restrict__ out) {
  __shared__ short As[16 * 264];  // 8.25 KiB; stride 264 shorts -> frag-read groups (l16+q)%8 uniform
  __shared__ short T[64 * 20];    // 2.5 KiB transpose buffer (EPI=0)
  int bid = blockIdx.x;
  int b = bid & 31;               // batch-minor: XCD pinning for Bt L2 residency
  int row0 = (bid >> 5) * 16;     // 128 row-blocks
  int t = threadIdx.x;
  int lane = t & 63, wv = t >> 6, l16 = lane & 15, quad = lane >> 4;

  const float* Ab = adj + (size_t)b * NN * NN + (size_t)row0 * NN;
  const uint16_t* Bb = Bt + (size_t)b * FF * NN + (size_t)(wv * 16 + l16) * NN;

  int sr = t >> 4;             // staging: 16 threads per row, 64 B contiguous each
  int sc = (t & 15) * 16;      // float (==short) column
  const float* ap = Ab + (size_t)sr * NN + sc;

  float4 areg[4];
#pragma unroll
  for (int i = 0; i < 4; ++i) areg[i] = *(const float4*)(ap + i * 4);

  f32x4 acc = {};
  for (int kc = 0; kc < 8; ++kc) {
    __syncthreads();  // prior iter frag reads done
    uint32_t p[8];
#pragma unroll
    for (int i = 0; i < 4; ++i) {
      p[2 * i]     = f2bf(areg[i].x) | ((uint32_t)f2bf(areg[i].y) << 16);
      p[2 * i + 1] = f2bf(areg[i].z) | ((uint32_t)f2bf(areg[i].w) << 16);
    }
    uint4 w0 = {p[0], p[1], p[2], p[3]};
    uint4 w1 = {p[4], p[5], p[6], p[7]};
    ((uint4*)&As[sr * 264 + sc])[0] = w0;
    ((uint4*)&As[sr * 264 + sc])[1] = w1;
    __syncthreads();
    if (kc < 7) {  // register prefetch of next K-chunk (contiguous 64 B/thread)
      const float* np = ap + (kc + 1) * 256;
#pragma unroll
      for (int i = 0; i < 4; ++i) areg[i] = *(const float4*)(np + i * 4);
    }
    const uint16_t* brow = Bb + kc * 256;
#pragma unroll
    for (int s = 0; s < 8; ++s) {
      bf16x8 a = *(const bf16x8*)&As[l16 * 264 + s * 32 + quad * 8];
      bf16x8 bq = *(const bf16x8*)(brow + s * 32 + quad * 8);
      acc = __builtin_amdgcn_mfma_f32_16x16x32_bf16(a, bq, acc, 0, 0, 0);
    }
  }

  int f = wv * 16 + l16;
  if (EPI == 0) {
#pragma unroll
    for (int r = 0; r < 4; ++r)
      Yn[((size_t)b * NN + row0 + quad * 4 + r) * FF + f] = f2bf(acc[r]);
    uint32_t q0 = f2bf(acc[0]) | ((uint32_t)f2bf(acc[1]) << 16);
    uint32_t q1 = f2bf(acc[2]) | ((uint32_t)f2bf(acc[3]) << 16);
    uint2 qv = {q0, q1};
    *(uint2*)&T[f * 20 + quad * 4] = qv;
    __syncthreads();
    int f2 = t >> 2, nc = (t & 3) * 4;
    uint2 w2 = *(const uint2*)&T[f2 * 20 + nc];
    *(uint2*)(Yt + ((size_t)b * FF + f2) * NN + row0 + nc) = w2;
  } else {
    float ka = Kc[0] - Kc[2], kb = Kc[1], kc2 = 2.0f * Kc[2];
    float bv = bias[f];
#pragma unroll
    for (int r = 0; r < 4; ++r) {
      size_t idx = ((size_t)b * NN + row0 + quad * 4 + r) * FF + f;
      out[idx] = ka * bf2f(xw[idx]) + kb * bf2f(y1[idx]) + kc2 * acc[r] + bv;
    }
  }
}

extern "C" void kernel_launch(void* const* d_in, const int* in_sizes, int n_in,
                              void* d_out, int out_size, void* d_ws, size_t ws_size,
                              hipStream_t stream) {
  const float* x    = (const float*)d_in[0];
  const float* adj  = (const float*)d_in[1];
  const float* W    = (const float*)d_in[2];
  const float* K    = (const float*)d_in[3];
  const float* bias = (const float*)d_in[4];
  float* out = (float*)d_out;

  uint8_t* ws = (uint8_t*)d_ws;
  const size_t SZ = (size_t)NB * NN * FF * sizeof(uint16_t);  // 8 MiB per buffer
  uint16_t* xw_n = (uint16_t*)(ws);
  uint16_t* xwT  = (uint16_t*)(ws + SZ);
  uint16_t* y1_n = (uint16_t*)(ws + 2 * SZ);
  uint16_t* y1T  = (uint16_t*)(ws + 3 * SZ);
  uint16_t* Wt   = (uint16_t*)(ws + 4 * SZ);

  k_prep<<<dim3(1), dim3(256), 0, stream>>>(W, Wt);
  k_xw<<<dim3(4096), dim3(256), 0, stream>>>(x, Wt, xw_n, xwT);
  k_gemm<0><<<dim3(4096), dim3(256), 0, stream>>>(adj, xwT, y1_n, y1T,
                                                  nullptr, nullptr, nullptr, nullptr, nullptr);
  k_gemm<1><<<dim3(4096), dim3(256), 0, stream>>>(adj, y1T, nullptr, nullptr,
                                                  xw_n, y1_n, K, bias, out);
}

// Round 3
// 967.934 us; speedup vs baseline: 1.0013x; 1.0013x over previous
//
#include <hip/hip_runtime.h>
#include <stdint.h>

#define NN 2048
#define FF 64
#define NB 32

typedef __attribute__((ext_vector_type(8))) short bf16x8;
typedef __attribute__((ext_vector_type(4))) float f32x4;

__device__ __forceinline__ uint16_t f2bf(float f) {
  uint32_t u = __builtin_bit_cast(uint32_t, f);
  return (uint16_t)((u + 0x7FFFu + ((u >> 16) & 1u)) >> 16);  // RNE
}
__device__ __forceinline__ float bf2f(uint16_t h) {
  uint32_t u = ((uint32_t)h) << 16;
  return __builtin_bit_cast(float, u);
}

// ---------------- W [64(k)][64(f)] fp32 -> Wt [64(f)][64(k)] bf16 ----------------
__global__ void k_prep(const float* __restrict__ W, uint16_t* __restrict__ Wt) {
  int t = threadIdx.x;  // 256
  for (int i = 0; i < 16; ++i) {
    int idx = t * 16 + i;  // = k*64 + f
    int k = idx >> 6, f = idx & 63;
    Wt[f * 64 + k] = f2bf(W[idx]);
  }
}

// ---------------- xw = x @ W ; writes xw_n [b][n][f] AND xwT [b][f][n] -----------
__global__ __launch_bounds__(256, 4) void k_xw(const float* __restrict__ x,
                                               const uint16_t* __restrict__ Wt,
                                               uint16_t* __restrict__ xw_n,
                                               uint16_t* __restrict__ xwT) {
  __shared__ short Xs[16 * 72];
  __shared__ short T[64 * 20];
  int bid = blockIdx.x;
  int b = bid & 31;
  int row0 = (bid >> 5) * 16;
  int t = threadIdx.x;
  int lane = t & 63, wv = t >> 6, l16 = lane & 15, quad = lane >> 4;

  int sr = t >> 4, sc = (t & 15) * 4;
  float4 v = *(const float4*)(x + ((size_t)b * NN + row0 + sr) * FF + sc);
  uint32_t p0 = f2bf(v.x) | ((uint32_t)f2bf(v.y) << 16);
  uint32_t p1 = f2bf(v.z) | ((uint32_t)f2bf(v.w) << 16);
  uint2 pv = {p0, p1};
  *(uint2*)&Xs[sr * 72 + sc] = pv;
  __syncthreads();

  f32x4 acc = {};
#pragma unroll
  for (int s = 0; s < 2; ++s) {
    bf16x8 a = *(const bf16x8*)&Xs[l16 * 72 + s * 32 + quad * 8];
    bf16x8 bq = *(const bf16x8*)(Wt + (size_t)(wv * 16 + l16) * 64 + s * 32 + quad * 8);
    acc = __builtin_amdgcn_mfma_f32_16x16x32_bf16(a, bq, acc, 0, 0, 0);
  }
  int f = wv * 16 + l16;
#pragma unroll
  for (int r = 0; r < 4; ++r)
    xw_n[((size_t)b * NN + row0 + quad * 4 + r) * FF + f] = f2bf(acc[r]);
  uint32_t q0 = f2bf(acc[0]) | ((uint32_t)f2bf(acc[1]) << 16);
  uint32_t q1 = f2bf(acc[2]) | ((uint32_t)f2bf(acc[3]) << 16);
  uint2 qv = {q0, q1};
  *(uint2*)&T[f * 20 + quad * 4] = qv;
  __syncthreads();
  int f2 = t >> 2, nc = (t & 3) * 4;
  uint2 w2 = *(const uint2*)&T[f2 * 20 + nc];
  *(uint2*)(xwT + ((size_t)b * FF + f2) * NN + row0 + nc) = w2;
}

// ---------------- Y = A @ X ; A fp32 [2048][2048], Bt bf16 [64][2048] ------------
// Block swizzle: xcd = bid&7 pins one batch per XCD at a time so the 256 KiB
// Bt slice stays L2-resident while adj streams (R2 post-mortem: batch-minor
// ordering put 8 MiB of B working set on a 4 MiB L2 -> ~1 GiB HBM re-fetch).
template <int EPI>
__global__ __launch_bounds__(256, 4) void k_gemm(const float* __restrict__ adj,
                                                 const uint16_t* __restrict__ Bt,
                                                 uint16_t* __restrict__ Yn,
                                                 uint16_t* __restrict__ Yt,
                                                 const uint16_t* __restrict__ xw,
                                                 const uint16_t* __restrict__ y1,
                                                 const float* __restrict__ Kc,
                                                 const float* __restrict__ bias,
                                                 float* __restrict__ out) {
  __shared__ short As[16 * 264];  // stride 264: frag-read bank groups (l16+q)%8 uniform
  __shared__ short T[64 * 20];
  int bid = blockIdx.x;
  int xcd = bid & 7;
  int i = bid >> 3;                 // 0..511
  int b = xcd + 8 * (i >> 7);       // XCD x: batches x, x+8, x+16, x+24 sequentially
  int row0 = (i & 127) * 16;
  int t = threadIdx.x;
  int lane = t & 63, wv = t >> 6, l16 = lane & 15, quad = lane >> 4;

  const float* Ab = adj + (size_t)b * NN * NN + (size_t)row0 * NN;
  const uint16_t* Bb = Bt + (size_t)b * FF * NN + (size_t)(wv * 16 + l16) * NN;

  int sr = t >> 4;             // staging: 16 threads per row, 64 B contiguous each
  int sc = (t & 15) * 16;
  const float* ap = Ab + (size_t)sr * NN + sc;

  float4 areg[4];
#pragma unroll
  for (int j = 0; j < 4; ++j) areg[j] = *(const float4*)(ap + j * 4);

  f32x4 acc = {};
  for (int kc = 0; kc < 8; ++kc) {
    __syncthreads();  // prior iter frag reads done
    uint32_t p[8];
#pragma unroll
    for (int j = 0; j < 4; ++j) {
      p[2 * j]     = f2bf(areg[j].x) | ((uint32_t)f2bf(areg[j].y) << 16);
      p[2 * j + 1] = f2bf(areg[j].z) | ((uint32_t)f2bf(areg[j].w) << 16);
    }
    uint4 w0 = {p[0], p[1], p[2], p[3]};
    uint4 w1 = {p[4], p[5], p[6], p[7]};
    ((uint4*)&As[sr * 264 + sc])[0] = w0;
    ((uint4*)&As[sr * 264 + sc])[1] = w1;
    __syncthreads();
    if (kc < 7) {  // register prefetch of next K-chunk
      const float* np = ap + (kc + 1) * 256;
#pragma unroll
      for (int j = 0; j < 4; ++j) areg[j] = *(const float4*)(np + j * 4);
    }
    const uint16_t* brow = Bb + kc * 256;
#pragma unroll
    for (int s = 0; s < 8; ++s) {
      bf16x8 a = *(const bf16x8*)&As[l16 * 264 + s * 32 + quad * 8];
      bf16x8 bq = *(const bf16x8*)(brow + s * 32 + quad * 8);
      acc = __builtin_amdgcn_mfma_f32_16x16x32_bf16(a, bq, acc, 0, 0, 0);
    }
  }

  int f = wv * 16 + l16;
  if (EPI == 0) {
#pragma unroll
    for (int r = 0; r < 4; ++r)
      Yn[((size_t)b * NN + row0 + quad * 4 + r) * FF + f] = f2bf(acc[r]);
    uint32_t q0 = f2bf(acc[0]) | ((uint32_t)f2bf(acc[1]) << 16);
    uint32_t q1 = f2bf(acc[2]) | ((uint32_t)f2bf(acc[3]) << 16);
    uint2 qv = {q0, q1};
    *(uint2*)&T[f * 20 + quad * 4] = qv;
    __syncthreads();
    int f2 = t >> 2, nc = (t & 3) * 4;
    uint2 w2 = *(const uint2*)&T[f2 * 20 + nc];
    *(uint2*)(Yt + ((size_t)b * FF + f2) * NN + row0 + nc) = w2;
  } else {
    float ka = Kc[0] - Kc[2], kb = Kc[1], kc2 = 2.0f * Kc[2];
    float bv = bias[f];
#pragma unroll
    for (int r = 0; r < 4; ++r) {
      size_t idx = ((size_t)b * NN + row0 + quad * 4 + r) * FF + f;
      out[idx] = ka * bf2f(xw[idx]) + kb * bf2f(y1[idx]) + kc2 * acc[r] + bv;
    }
  }
}

extern "C" void kernel_launch(void* const* d_in, const int* in_sizes, int n_in,
                              void* d_out, int out_size, void* d_ws, size_t ws_size,
                              hipStream_t stream) {
  const float* x    = (const float*)d_in[0];
  const float* adj  = (const float*)d_in[1];
  const float* W    = (const float*)d_in[2];
  const float* K    = (const float*)d_in[3];
  const float* bias = (const float*)d_in[4];
  float* out = (float*)d_out;

  uint8_t* ws = (uint8_t*)d_ws;
  const size_t SZ = (size_t)NB * NN * FF * sizeof(uint16_t);  // 8 MiB per buffer
  uint16_t* xw_n = (uint16_t*)(ws);
  uint16_t* xwT  = (uint16_t*)(ws + SZ);
  uint16_t* y1_n = (uint16_t*)(ws + 2 * SZ);
  uint16_t* y1T  = (uint16_t*)(ws + 3 * SZ);
  uint16_t* Wt   = (uint16_t*)(ws + 4 * SZ);

  k_prep<<<dim3(1), dim3(256), 0, stream>>>(W, Wt);
  k_xw<<<dim3(4096), dim3(256), 0, stream>>>(x, Wt, xw_n, xwT);
  k_gemm<0><<<dim3(4096), dim3(256), 0, stream>>>(adj, xwT, y1_n, y1T,
                                                  nullptr, nullptr, nullptr, nullptr, nullptr);
  k_gemm<1><<<dim3(4096), dim3(256), 0, stream>>>(adj, y1T, nullptr, nullptr,
                                                  xw_n, y1_n, K, bias, out);
}